// Round 5
// baseline (77.831 us; speedup 1.0000x reference)
//
#include <hip/hip_runtime.h>
#include <cmath>

#define IMG_W 1024
#define SROWS 22              // staged source rows (16 outputs + 6 halo)
#define SCST  73              // LDS row stride in float4 (72 used, odd stride)
#define NCHUNK 18             // float4 col-chunks staged per row (72 cols)
#define NITEMS (SROWS * NCHUNK)   // 396

// separable Gaussian: w(ky,kx) = gv[ky]*gh[kx], 1/(8*pi) folded into gv
struct GK { float gh[7]; float gv[7]; };

// bank-spread swizzle on float4 column index (bijective within each 8-block)
__device__ __forceinline__ int swz(int c) { return c ^ ((c >> 3) & 7); }

// non-temporal float4 load (no L2 allocation -> no dirty-poison eviction)
typedef float f4v __attribute__((ext_vector_type(4)));
__device__ __forceinline__ float4 ntload4(const float* p) {
    const f4v v = __builtin_nontemporal_load((const f4v*)p);
    return make_float4(v.x, v.y, v.z, v.w);
}

__device__ __forceinline__ float warp_block_sum(float v, float* wsum, int tx, int ty) {
    #pragma unroll
    for (int off = 32; off > 0; off >>= 1)
        v += __shfl_down(v, off, 64);
    if (tx == 0) wsum[ty] = v;
    __syncthreads();
    return wsum[0] + wsum[1] + wsum[2] + wsum[3];
}

// pointwise MIND fields from the 7 source vectors; write to swizzled LDS slots
__device__ __forceinline__ void field_write(const float4* __restrict__ L,
                                            int r, int j, float4* __restrict__ s1)
{
    const float4 a = L[0], b = L[1], c2 = L[2], d = L[3];
    const float4 u = L[4], ub = L[5], uc = L[6];
    float4* __restrict__ dst = &s1[r * SCST];
    #define MIND_FIELD(E, K) { \
        const float a2 = a.E * a.E; \
        const float tb = a.E - b.E, tc = a.E - c2.E, td = a.E - d.E; \
        const float su = u.E - ub.E, sv = u.E - uc.E; \
        float4 f; \
        f.x = fmaf(tb, tb, -a2);                           /* H */ \
        f.y = fmaf(tc, tc, -a2);                           /* V */ \
        f.z = fmaf(td, td, -a2);                           /* D */ \
        f.w = fmaf(u.E, u.E + u.E, fmaf(su, su, sv * sv)); /* U */ \
        dst[swz(4 * j + K)] = f; }
    MIND_FIELD(x, 0)
    MIND_FIELD(y, 1)
    MIND_FIELD(z, 2)
    MIND_FIELD(w, 3)
    #undef MIND_FIELD
}

__global__ __launch_bounds__(256, 4)
void mind_tile(const float* __restrict__ img1, const float* __restrict__ img2,
               float* __restrict__ partials, GK gk)
{
    __shared__ float4 s1[SROWS * SCST];    // 25696 B -> 4 blocks/CU (grid-limited)

    const int tx  = (int)threadIdx.x;       // 0..63 : output col owner
    const int ty  = (int)threadIdx.y;       // 0..3  : 4-row group owner (== wave id)
    const int tid = ty * 64 + tx;
    // straddle-first launch-order remap (bijective relabel; partials keep real ids)
    const int bx  = ((int)blockIdx.x + 7)  & 15;
    const int by  = ((int)blockIdx.y + 31) & 63;
    const int x0  = 7 + 64 * bx;            // first output col of tile
    const int y0  = 7 + 16 * by;            // first output row of tile
    const int x4  = x0 - 3;                 // float4-aligned staged origin

    // ---- phase A: pointwise fields -> LDS --------------------------------
    // Issue ALL global loads (nt, no-allocate) for both items up front to
    // maximize memory-level parallelism, then compute + swizzled ds_write.
    const int rA = tid / NCHUNK, jA = tid - rA * NCHUNK;           // item A: always valid
    const int itB = tid + 256;
    const int rB = itB / NCHUNK, jB = itB - rB * NCHUNK;
    const bool hasB = (itB < NITEMS);                              // item B: tid < 140

    float4 LA[7], LB[7];
    {
        const int srA  = min(y0 - 3 + rA, 1023);
        const int srpA = srA ^ 512;
        const int sccA = min(x4 + 4 * jA, 1020);
        const int scpA = sccA ^ 512;
        LA[0] = ntload4(&img2[srA  * IMG_W + sccA]);
        LA[1] = ntload4(&img2[srA  * IMG_W + scpA]);
        LA[2] = ntload4(&img2[srpA * IMG_W + sccA]);
        LA[3] = ntload4(&img2[srpA * IMG_W + scpA]);
        LA[4] = ntload4(&img1[srA  * IMG_W + sccA]);
        LA[5] = ntload4(&img1[srA  * IMG_W + scpA]);
        LA[6] = ntload4(&img1[srpA * IMG_W + sccA]);
        if (hasB) {
            const int srB  = min(y0 - 3 + rB, 1023);
            const int srpB = srB ^ 512;
            const int sccB = min(x4 + 4 * jB, 1020);
            const int scpB = sccB ^ 512;
            LB[0] = ntload4(&img2[srB  * IMG_W + sccB]);
            LB[1] = ntload4(&img2[srB  * IMG_W + scpB]);
            LB[2] = ntload4(&img2[srpB * IMG_W + sccB]);
            LB[3] = ntload4(&img2[srpB * IMG_W + scpB]);
            LB[4] = ntload4(&img1[srB  * IMG_W + sccB]);
            LB[5] = ntload4(&img1[srB  * IMG_W + scpB]);
            LB[6] = ntload4(&img1[srpB * IMG_W + sccB]);
        }
    }
    field_write(LA, rA, jA, s1);
    if (hasB) field_write(LB, rB, jB, s1);
    __syncthreads();

    // straddle detection: boundary lies between 511 and 512
    const bool xs = (x0 - 3 <= 511) && (x0 + 66 >= 512);   // only bx==7
    const bool ys = (y0 - 3 <= 511) && (y0 + 18 >= 512);   // only by==31
    const bool straddle = xs || ys;            // block-uniform

    // ---- phase B: horizontal conv raw -> h, IN PLACE (non-straddle only) ----
    // 176 tasks: (row 0..21) x (8-col segment 0..7). All reads land in regs
    // before the barrier; writes go to slots swz(0..63) of the same row after.
    float4 hv[8];
    const int brow = tid >> 3, bseg = tid & 7;
    const bool btask = (!straddle) && (tid < 176);
    if (btask) {
        const float4* __restrict__ rb = &s1[brow * SCST];
        float4 f[14];
        #pragma unroll
        for (int q = 0; q < 14; ++q) f[q] = rb[swz(8 * bseg + q)];
        #pragma unroll
        for (int o = 0; o < 8; ++o) {
            float hH = 0, hV = 0, hD = 0, hU = 0;
            #pragma unroll
            for (int k = 0; k < 7; ++k) {
                const float4 g = f[o + k];
                hH = fmaf(gk.gh[k], g.x, hH);
                hV = fmaf(gk.gh[k], g.y, hV);
                hD = fmaf(gk.gh[k], g.z, hD);
                hU = fmaf(gk.gh[k], g.w, hU);
            }
            hv[o] = make_float4(hH, hV, hD, hU);
        }
    }
    __syncthreads();
    if (btask) {
        float4* __restrict__ rb = &s1[brow * SCST];
        #pragma unroll
        for (int o = 0; o < 8; ++o) rb[swz(8 * bseg + o)] = hv[o];
    }
    __syncthreads();

    const bool xok = (x0 + tx <= 1016);
    float tsum = 0.f;

    if (!straddle) {
        // ============ FAST path: vertical conv over precomputed h ============
        const int ci = swz(tx);
        float Px[4] = {0,0,0,0}, Py[4] = {0,0,0,0}, Pd[4] = {0,0,0,0}, V4[4] = {0,0,0,0};
        #pragma unroll
        for (int r = 0; r < 10; ++r) {
            const float4 h = s1[(4 * ty + r) * SCST + ci];
            #pragma unroll
            for (int o = 0; o < 4; ++o) {
                if (r - o >= 0 && r - o <= 6) {          // compile-time pruned
                    const float g = gk.gv[r - o];
                    Px[o] = fmaf(g, h.x, Px[o]);
                    Py[o] = fmaf(g, h.y, Py[o]);
                    Pd[o] = fmaf(g, h.z, Pd[o]);
                    V4[o] = fmaf(g, h.w, V4[o]);
                }
            }
        }
        #pragma unroll
        for (int o = 0; o < 4; ++o) {
            const float V = fmaf(V4[o], 0.25f, 1e-5f);
            const float invV = 1.0f / V;
            float M = fminf(0.f, Px[o]);
            M = fminf(M, Py[o]); M = fminf(M, Pd[o]);
            // 5 of the 8 near-shift maps equal T0 here -> join the 72 far shifts
            const float pix = 77.f * __expf(M * invV)
                + __expf((M - Px[o]) * invV)
                + __expf((M - Py[o]) * invV)
                + __expf((M - Pd[o]) * invV);
            const bool ok = xok && (y0 + 4 * ty + o <= 1017);
            tsum += ok ? pix : 0.f;
        }
    } else {
        // ============ GENERAL path: raw intact (phase B skipped) =============
        float glx[7], ghx[7];
        int cidx[7];
        #pragma unroll
        for (int kx = 0; kx < 7; ++kx) {
            const bool lo = (((x0 - 3 + tx + kx) & 512) == 0);
            glx[kx] = lo ? gk.gh[kx] : 0.f;
            ghx[kx] = lo ? 0.f : gk.gh[kx];
            cidx[kx] = swz(tx + kx);
        }
        float Ph[4]  = {0,0,0,0}, Qh[4]  = {0,0,0,0}, Pv[4] = {0,0,0,0}, Qv[4] = {0,0,0,0};
        float Ppp[4] = {0,0,0,0}, Ppm[4] = {0,0,0,0}, Pmp[4] = {0,0,0,0}, Pmm[4] = {0,0,0,0};
        float V4[4]  = {0,0,0,0};
        #pragma unroll
        for (int r = 0; r < 10; ++r) {
            const float4* __restrict__ row = &s1[(4 * ty + r) * SCST];
            float hHlo = 0, hHhi = 0, hV = 0, hDlo = 0, hDhi = 0, hU = 0;
            #pragma unroll
            for (int kx = 0; kx < 7; ++kx) {
                const float4 g = row[cidx[kx]];
                hHlo = fmaf(glx[kx],   g.x, hHlo);
                hHhi = fmaf(ghx[kx],   g.x, hHhi);
                hV   = fmaf(gk.gh[kx], g.y, hV);
                hDlo = fmaf(glx[kx],   g.z, hDlo);
                hDhi = fmaf(ghx[kx],   g.z, hDhi);
                hU   = fmaf(gk.gh[kx], g.w, hU);
            }
            const bool ylo = (((y0 + 4 * ty - 3 + r) & 512) == 0);
            #pragma unroll
            for (int o = 0; o < 4; ++o) {
                if (r - o >= 0 && r - o <= 6) {
                    const float g  = gk.gv[r - o];
                    const float wl = ylo ? g : 0.f;
                    const float wh = ylo ? 0.f : g;
                    Ph [o] = fmaf(g,  hHlo, Ph [o]);
                    Qh [o] = fmaf(g,  hHhi, Qh [o]);
                    Pv [o] = fmaf(wl, hV,   Pv [o]);
                    Qv [o] = fmaf(wh, hV,   Qv [o]);
                    Ppp[o] = fmaf(wl, hDlo, Ppp[o]);
                    Ppm[o] = fmaf(wh, hDlo, Ppm[o]);
                    Pmp[o] = fmaf(wl, hDhi, Pmp[o]);
                    Pmm[o] = fmaf(wh, hDhi, Pmm[o]);
                    V4 [o] = fmaf(g,  hU,   V4 [o]);
                }
            }
        }
        #pragma unroll
        for (int o = 0; o < 4; ++o) {
            const float V = fmaf(V4[o], 0.25f, 1e-5f);
            const float invV = 1.0f / V;
            float M = fminf(0.f, Ph[o]);
            M = fminf(M, Qh[o]);  M = fminf(M, Pv[o]);  M = fminf(M, Qv[o]);
            M = fminf(M, Ppp[o]); M = fminf(M, Pmp[o]); M = fminf(M, Ppm[o]); M = fminf(M, Pmm[o]);
            const float pix = 72.f * __expf(M * invV)
                + __expf((M - Ph [o]) * invV) + __expf((M - Qh [o]) * invV)
                + __expf((M - Pv [o]) * invV) + __expf((M - Qv [o]) * invV)
                + __expf((M - Ppp[o]) * invV) + __expf((M - Pmp[o]) * invV)
                + __expf((M - Ppm[o]) * invV) + __expf((M - Pmm[o]) * invV);
            const bool ok = xok && (y0 + 4 * ty + o <= 1017);
            tsum += ok ? pix : 0.f;
        }
    }

    // ---- per-block partial to workspace (NO fence, NO same-address atomics) ----
    __shared__ float wsum[4];
    const float bt = warp_block_sum(tsum, wsum, tx, ty);
    if (tid == 0)
        partials[by * 16 + bx] = bt;
}

__global__ __launch_bounds__(256)
void mind_reduce(const float* __restrict__ partials, float* __restrict__ out)
{
    // 1024 partials, one block
    float s = 0.f;
    #pragma unroll
    for (int k = 0; k < 4; ++k)
        s += partials[(int)threadIdx.x + 256 * k];
    double d = (double)s;
    #pragma unroll
    for (int off = 32; off > 0; off >>= 1)
        d += __shfl_down(d, off, 64);
    __shared__ double sm[4];
    const int lane = (int)threadIdx.x & 63, wid = (int)threadIdx.x >> 6;
    if (lane == 0) sm[wid] = d;
    __syncthreads();
    if (threadIdx.x == 0)
        out[0] = (float)((sm[0] + sm[1] + sm[2] + sm[3]) / 81688800.0);  // 80*1011*1010
}

extern "C" void kernel_launch(void* const* d_in, const int* in_sizes, int n_in,
                              void* d_out, int out_size, void* d_ws, size_t ws_size,
                              hipStream_t stream) {
    const float* img1 = (const float*)d_in[0];
    const float* img2 = (const float*)d_in[1];
    float* out = (float*)d_out;
    float* partials = (float*)d_ws;

    GK gk;
    for (int i = 0; i < 7; ++i) {
        const double dv = i - 3;
        gk.gh[i] = (float)std::exp(-(dv * dv) / 8.0);
        gk.gv[i] = (float)(std::exp(-(dv * dv) / 8.0) / (8.0 * M_PI));
    }

    dim3 block(64, 4);
    dim3 grid(16, 64);   // 1024 blocks, 64x16 tiles
    mind_tile<<<grid, block, 0, stream>>>(img1, img2, partials, gk);
    mind_reduce<<<1, 256, 0, stream>>>(partials, out);
}

// Round 6
// 72.330 us; speedup vs baseline: 1.0761x; 1.0761x over previous
//
#include <hip/hip_runtime.h>
#include <cmath>

#define IMG_W 1024
#define SROWS 22              // staged source rows (16 outputs + 6 halo)
#define SCST  73              // LDS row stride in float4 (72 used, odd stride)
#define NCHUNK 18             // float4 col-chunks staged per row (72 cols)
#define NITEMS (SROWS * NCHUNK)   // 396
#define FLAG_MAGIC 0xA5C3F00D5EED1234ULL

// separable Gaussian: w(ky,kx) = gv[ky]*gh[kx], 1/(8*pi) folded into gv
struct GK { float gh[7]; float gv[7]; };

// bank-spread swizzle on float4 column index (bijective within each 8-block)
__device__ __forceinline__ int swz(int c) { return c ^ ((c >> 3) & 7); }

__device__ __forceinline__ float warp_block_sum(float v, float* wsum, int tx, int ty) {
    #pragma unroll
    for (int off = 32; off > 0; off >>= 1)
        v += __shfl_down(v, off, 64);
    if (tx == 0) wsum[ty] = v;
    __syncthreads();
    return wsum[0] + wsum[1] + wsum[2] + wsum[3];
}

__global__ __launch_bounds__(256)
void mind_tile(const float* __restrict__ img1, const float* __restrict__ img2,
               float* __restrict__ partials, unsigned long long* __restrict__ flags,
               float* __restrict__ out, GK gk)
{
    __shared__ float4 s1[SROWS * SCST];    // 25696 B

    const int tx  = (int)threadIdx.x;       // 0..63 : output col owner
    const int ty  = (int)threadIdx.y;       // 0..3  : 4-row group owner (== wave id)
    const int tid = ty * 64 + tx;
    // straddle-first launch-order remap (bijective relabel; partials keep real ids)
    const int bx  = ((int)blockIdx.x + 7)  & 15;
    const int by  = ((int)blockIdx.y + 31) & 63;
    const int x0  = 7 + 64 * bx;            // first output col of tile
    const int y0  = 7 + 16 * by;            // first output row of tile
    const int x4  = x0 - 3;                 // float4-aligned staged origin

    // ---- phase A: pointwise fields -> LDS (float4 loads, swizzled writes) ----
    #pragma unroll
    for (int ii = 0; ii < 2; ++ii) {
        const int it = tid + 256 * ii;
        if (it < NITEMS) {
            const int r   = it / NCHUNK;
            const int j   = it - r * NCHUNK;
            const int sr  = min(y0 - 3 + r, 1023);   // clamp feeds only masked outputs
            const int srp = sr ^ 512;                // only in-bounds y-shift source
            const int scc = min(x4 + 4 * j, 1020);   // 4-aligned, in-bounds
            const int scp = scc ^ 512;               // only in-bounds x-shift source
            const float4 a  = *(const float4*)&img2[sr  * IMG_W + scc];
            const float4 b  = *(const float4*)&img2[sr  * IMG_W + scp];
            const float4 c2 = *(const float4*)&img2[srp * IMG_W + scc];
            const float4 d  = *(const float4*)&img2[srp * IMG_W + scp];
            const float4 u  = *(const float4*)&img1[sr  * IMG_W + scc];
            const float4 ub = *(const float4*)&img1[sr  * IMG_W + scp];
            const float4 uc = *(const float4*)&img1[srp * IMG_W + scc];
            float4* __restrict__ dst = &s1[r * SCST];
            #define MIND_FIELD(E, K) { \
                const float a2 = a.E * a.E; \
                const float tb = a.E - b.E, tc = a.E - c2.E, td = a.E - d.E; \
                const float su = u.E - ub.E, sv = u.E - uc.E; \
                float4 f; \
                f.x = fmaf(tb, tb, -a2);                           /* H */ \
                f.y = fmaf(tc, tc, -a2);                           /* V */ \
                f.z = fmaf(td, td, -a2);                           /* D */ \
                f.w = fmaf(u.E, u.E + u.E, fmaf(su, su, sv * sv)); /* U */ \
                dst[swz(4 * j + K)] = f; }
            MIND_FIELD(x, 0)
            MIND_FIELD(y, 1)
            MIND_FIELD(z, 2)
            MIND_FIELD(w, 3)
            #undef MIND_FIELD
        }
    }
    __syncthreads();

    // straddle detection: boundary lies between 511 and 512
    const bool xs = (x0 - 3 <= 511) && (x0 + 66 >= 512);   // only bx==7
    const bool ys = (y0 - 3 <= 511) && (y0 + 18 >= 512);   // only by==31
    const bool straddle = xs || ys;            // block-uniform

    // ---- phase B: horizontal conv raw -> h, IN PLACE (non-straddle only) ----
    float4 hv[8];
    const int brow = tid >> 3, bseg = tid & 7;
    const bool btask = (!straddle) && (tid < 176);
    if (btask) {
        const float4* __restrict__ rb = &s1[brow * SCST];
        float4 f[14];
        #pragma unroll
        for (int q = 0; q < 14; ++q) f[q] = rb[swz(8 * bseg + q)];
        #pragma unroll
        for (int o = 0; o < 8; ++o) {
            float hH = 0, hV = 0, hD = 0, hU = 0;
            #pragma unroll
            for (int k = 0; k < 7; ++k) {
                const float4 g = f[o + k];
                hH = fmaf(gk.gh[k], g.x, hH);
                hV = fmaf(gk.gh[k], g.y, hV);
                hD = fmaf(gk.gh[k], g.z, hD);
                hU = fmaf(gk.gh[k], g.w, hU);
            }
            hv[o] = make_float4(hH, hV, hD, hU);
        }
    }
    __syncthreads();
    if (btask) {
        float4* __restrict__ rb = &s1[brow * SCST];
        #pragma unroll
        for (int o = 0; o < 8; ++o) rb[swz(8 * bseg + o)] = hv[o];
    }
    __syncthreads();

    const bool xok = (x0 + tx <= 1016);
    float tsum = 0.f;

    if (!straddle) {
        // ============ FAST path: vertical conv over precomputed h ============
        const int ci = swz(tx);
        float Px[4] = {0,0,0,0}, Py[4] = {0,0,0,0}, Pd[4] = {0,0,0,0}, V4[4] = {0,0,0,0};
        #pragma unroll
        for (int r = 0; r < 10; ++r) {
            const float4 h = s1[(4 * ty + r) * SCST + ci];
            #pragma unroll
            for (int o = 0; o < 4; ++o) {
                if (r - o >= 0 && r - o <= 6) {          // compile-time pruned
                    const float g = gk.gv[r - o];
                    Px[o] = fmaf(g, h.x, Px[o]);
                    Py[o] = fmaf(g, h.y, Py[o]);
                    Pd[o] = fmaf(g, h.z, Pd[o]);
                    V4[o] = fmaf(g, h.w, V4[o]);
                }
            }
        }
        #pragma unroll
        for (int o = 0; o < 4; ++o) {
            const float V = fmaf(V4[o], 0.25f, 1e-5f);
            const float invV = 1.0f / V;
            float M = fminf(0.f, Px[o]);
            M = fminf(M, Py[o]); M = fminf(M, Pd[o]);
            // 5 of the 8 near-shift maps equal T0 here -> join the 72 far shifts
            const float pix = 77.f * __expf(M * invV)
                + __expf((M - Px[o]) * invV)
                + __expf((M - Py[o]) * invV)
                + __expf((M - Pd[o]) * invV);
            const bool ok = xok && (y0 + 4 * ty + o <= 1017);
            tsum += ok ? pix : 0.f;
        }
    } else {
        // ============ GENERAL path: raw intact (phase B skipped) =============
        float glx[7], ghx[7];
        int cidx[7];
        #pragma unroll
        for (int kx = 0; kx < 7; ++kx) {
            const bool lo = (((x0 - 3 + tx + kx) & 512) == 0);
            glx[kx] = lo ? gk.gh[kx] : 0.f;
            ghx[kx] = lo ? 0.f : gk.gh[kx];
            cidx[kx] = swz(tx + kx);
        }
        float Ph[4]  = {0,0,0,0}, Qh[4]  = {0,0,0,0}, Pv[4] = {0,0,0,0}, Qv[4] = {0,0,0,0};
        float Ppp[4] = {0,0,0,0}, Ppm[4] = {0,0,0,0}, Pmp[4] = {0,0,0,0}, Pmm[4] = {0,0,0,0};
        float V4[4]  = {0,0,0,0};
        #pragma unroll
        for (int r = 0; r < 10; ++r) {
            const float4* __restrict__ row = &s1[(4 * ty + r) * SCST];
            float hHlo = 0, hHhi = 0, hV = 0, hDlo = 0, hDhi = 0, hU = 0;
            #pragma unroll
            for (int kx = 0; kx < 7; ++kx) {
                const float4 g = row[cidx[kx]];
                hHlo = fmaf(glx[kx],   g.x, hHlo);
                hHhi = fmaf(ghx[kx],   g.x, hHhi);
                hV   = fmaf(gk.gh[kx], g.y, hV);
                hDlo = fmaf(glx[kx],   g.z, hDlo);
                hDhi = fmaf(ghx[kx],   g.z, hDhi);
                hU   = fmaf(gk.gh[kx], g.w, hU);
            }
            const bool ylo = (((y0 + 4 * ty - 3 + r) & 512) == 0);
            #pragma unroll
            for (int o = 0; o < 4; ++o) {
                if (r - o >= 0 && r - o <= 6) {
                    const float g  = gk.gv[r - o];
                    const float wl = ylo ? g : 0.f;
                    const float wh = ylo ? 0.f : g;
                    Ph [o] = fmaf(g,  hHlo, Ph [o]);
                    Qh [o] = fmaf(g,  hHhi, Qh [o]);
                    Pv [o] = fmaf(wl, hV,   Pv [o]);
                    Qv [o] = fmaf(wh, hV,   Qv [o]);
                    Ppp[o] = fmaf(wl, hDlo, Ppp[o]);
                    Ppm[o] = fmaf(wh, hDlo, Ppm[o]);
                    Pmp[o] = fmaf(wl, hDhi, Pmp[o]);
                    Pmm[o] = fmaf(wh, hDhi, Pmm[o]);
                    V4 [o] = fmaf(g,  hU,   V4 [o]);
                }
            }
        }
        #pragma unroll
        for (int o = 0; o < 4; ++o) {
            const float V = fmaf(V4[o], 0.25f, 1e-5f);
            const float invV = 1.0f / V;
            float M = fminf(0.f, Ph[o]);
            M = fminf(M, Qh[o]);  M = fminf(M, Pv[o]);  M = fminf(M, Qv[o]);
            M = fminf(M, Ppp[o]); M = fminf(M, Pmp[o]); M = fminf(M, Ppm[o]); M = fminf(M, Pmm[o]);
            const float pix = 72.f * __expf(M * invV)
                + __expf((M - Ph [o]) * invV) + __expf((M - Qh [o]) * invV)
                + __expf((M - Pv [o]) * invV) + __expf((M - Qv [o]) * invV)
                + __expf((M - Ppp[o]) * invV) + __expf((M - Pmp[o]) * invV)
                + __expf((M - Ppm[o]) * invV) + __expf((M - Pmm[o]) * invV);
            const bool ok = xok && (y0 + 4 * ty + o <= 1017);
            tsum += ok ? pix : 0.f;
        }
    }

    // ---- publish per-block partial: fence-free, atomic-RMW only ------------
    __shared__ float wsum[4];
    const float bt = warp_block_sum(tsum, wsum, tx, ty);
    const int pidx = by * 16 + bx;
    if (tid == 0) {
        // device-scope RMW: coherent at fabric, NO L2 flush (unlike __threadfence)
        float old = atomicExch(&partials[pidx], bt);
        asm volatile("" :: "v"(old));   // consume -> s_waitcnt: exch complete before flag
        atomicExch(&flags[pidx], FLAG_MAGIC ^ (unsigned long long)pidx);
    }

    // ---- last-launched raw block reduces (replaces 2nd kernel, no fence) ----
    if (blockIdx.x == 15 && blockIdx.y == 63) {
        float s = 0.f;
        #pragma unroll
        for (int k = 0; k < 4; ++k) {
            const int idx = tid + 256 * k;
            const unsigned long long want = FLAG_MAGIC ^ (unsigned long long)idx;
            while (__hip_atomic_load(&flags[idx], __ATOMIC_RELAXED,
                                     __HIP_MEMORY_SCOPE_AGENT) != want)
                __builtin_amdgcn_s_sleep(8);
            s += __hip_atomic_load(&partials[idx], __ATOMIC_RELAXED,
                                   __HIP_MEMORY_SCOPE_AGENT);
        }
        // bit-identical to the old mind_reduce kernel
        double d = (double)s;
        #pragma unroll
        for (int off = 32; off > 0; off >>= 1)
            d += __shfl_down(d, off, 64);
        __shared__ double sm[4];
        if (tx == 0) sm[ty] = d;
        __syncthreads();
        if (tid == 0)
            out[0] = (float)((sm[0] + sm[1] + sm[2] + sm[3]) / 81688800.0);  // 80*1011*1010
    }
}

extern "C" void kernel_launch(void* const* d_in, const int* in_sizes, int n_in,
                              void* d_out, int out_size, void* d_ws, size_t ws_size,
                              hipStream_t stream) {
    const float* img1 = (const float*)d_in[0];
    const float* img2 = (const float*)d_in[1];
    float* out = (float*)d_out;
    float* partials = (float*)d_ws;
    unsigned long long* flags = (unsigned long long*)((char*)d_ws + 8192);

    GK gk;
    for (int i = 0; i < 7; ++i) {
        const double dv = i - 3;
        gk.gh[i] = (float)std::exp(-(dv * dv) / 8.0);
        gk.gv[i] = (float)(std::exp(-(dv * dv) / 8.0) / (8.0 * M_PI));
    }

    dim3 block(64, 4);
    dim3 grid(16, 64);   // 1024 blocks, 64x16 tiles
    mind_tile<<<grid, block, 0, stream>>>(img1, img2, partials, flags, out, gk);
}

// Round 7
// 69.895 us; speedup vs baseline: 1.1135x; 1.0348x over previous
//
#include <hip/hip_runtime.h>
#include <cmath>

#define IMG_W 1024
#define SROWS 22              // staged source rows  (16 outputs + 6 halo)
#define SCOLS 73              // 72 staged cols (18 float4 chunks) + 1 pad col

// separable Gaussian: w(ky,kx) = gv[ky]*gh[kx], 1/(8*pi) folded into gv
struct GK { float gh[7]; float gv[7]; };

__device__ __forceinline__ float warp_block_sum(float v, float* wsum, int tx, int ty) {
    #pragma unroll
    for (int off = 32; off > 0; off >>= 1)
        v += __shfl_down(v, off, 64);
    if (tx == 0) wsum[ty] = v;
    __syncthreads();
    return wsum[0] + wsum[1] + wsum[2] + wsum[3];
}

__global__ __launch_bounds__(256)
void mind_tile(const float* __restrict__ img1, const float* __restrict__ img2,
               float* __restrict__ partials, GK gk)
{
    __shared__ float4 s1[SROWS * SCOLS];    // 25696 B

    const int tx  = (int)threadIdx.x;       // 0..63 : output col owner
    const int ty  = (int)threadIdx.y;       // 0..3  : 4-row group owner (== wave id)
    const int tid = ty * 64 + tx;
    const int x0  = 7 + 64 * (int)blockIdx.x;   // first output col of tile
    const int y0  = 7 + 16 * (int)blockIdx.y;   // first output row of tile
    const int x4  = x0 - 3;                     // = 64*bx + 4, float4-aligned

    // ---- stage 1: pointwise fields -> LDS, float4-vectorized ----
    // 22 rows x 18 float4 col-chunks; each xor-512 region is contiguous per
    // 4-aligned chunk (512 is 4-aligned), so all 7 source reads are dwordx4.
    // Chunk clamp to col 1020 only alters staged entries feeding masked outputs.
    #pragma unroll 2
    for (int it = tid; it < SROWS * 18; it += 256) {
        const int r   = it / 18;
        const int j   = it - r * 18;
        const int sr  = min(y0 - 3 + r, 1023);   // clamp feeds only masked outputs
        const int srp = sr ^ 512;                // the only in-bounds y-shift source
        const int scc = min(x4 + 4 * j, 1020);   // stays 4-aligned, in-bounds
        const int scp = scc ^ 512;               // the only in-bounds x-shift source
        const float4 a  = *(const float4*)&img2[sr  * IMG_W + scc];
        const float4 b  = *(const float4*)&img2[sr  * IMG_W + scp];
        const float4 c2 = *(const float4*)&img2[srp * IMG_W + scc];
        const float4 d  = *(const float4*)&img2[srp * IMG_W + scp];
        const float4 u  = *(const float4*)&img1[sr  * IMG_W + scc];
        const float4 ub = *(const float4*)&img1[sr  * IMG_W + scp];
        const float4 uc = *(const float4*)&img1[srp * IMG_W + scc];
        float4* __restrict__ dst = &s1[r * SCOLS + 4 * j];
        #define MIND_FIELD(E, K) { \
            const float a2 = a.E * a.E; \
            const float tb = a.E - b.E, tc = a.E - c2.E, td = a.E - d.E; \
            const float su = u.E - ub.E, sv = u.E - uc.E; \
            float4 f; \
            f.x = fmaf(tb, tb, -a2);                           /* H */ \
            f.y = fmaf(tc, tc, -a2);                           /* V */ \
            f.z = fmaf(td, td, -a2);                           /* D */ \
            f.w = fmaf(u.E, u.E + u.E, fmaf(su, su, sv * sv)); /* U */ \
            dst[K] = f; }
        MIND_FIELD(x, 0)
        MIND_FIELD(y, 1)
        MIND_FIELD(z, 2)
        MIND_FIELD(w, 3)
        #undef MIND_FIELD
    }
    __syncthreads();

    // x/y mask-split detection: boundary lies between 511 and 512
    const bool xs = (x0 - 3 <= 511) && (x0 + 66 >= 512);   // only bx==7
    const bool ys = (y0 - 3 <= 511) && (y0 + 18 >= 512);   // only by==31
    const bool xok = (x0 + tx <= 1016);
    float tsum = 0.f;

    if (!xs && !ys) {
        // ================= FAST path: block-uniform masks (92% of blocks) ======
        float Px[4] = {0,0,0,0}, Py[4] = {0,0,0,0}, Pd[4] = {0,0,0,0}, V4[4] = {0,0,0,0};
        #pragma unroll
        for (int r = 0; r < 10; ++r) {
            const float4* __restrict__ row = &s1[(4 * ty + r) * SCOLS + tx];
            float hH = 0, hV = 0, hD = 0, hU = 0;
            #pragma unroll
            for (int kx = 0; kx < 7; ++kx) {
                const float4 g = row[kx];
                hH = fmaf(gk.gh[kx], g.x, hH);
                hV = fmaf(gk.gh[kx], g.y, hV);
                hD = fmaf(gk.gh[kx], g.z, hD);
                hU = fmaf(gk.gh[kx], g.w, hU);
            }
            #pragma unroll
            for (int o = 0; o < 4; ++o) {
                if (r - o >= 0 && r - o <= 6) {          // compile-time pruned
                    const float g = gk.gv[r - o];
                    Px[o] = fmaf(g, hH, Px[o]);
                    Py[o] = fmaf(g, hV, Py[o]);
                    Pd[o] = fmaf(g, hD, Pd[o]);
                    V4[o] = fmaf(g, hU, V4[o]);
                }
            }
        }
        #pragma unroll
        for (int o = 0; o < 4; ++o) {
            const float V = fmaf(V4[o], 0.25f, 1e-5f);
            const float invV = 1.0f / V;
            float M = fminf(0.f, Px[o]);
            M = fminf(M, Py[o]); M = fminf(M, Pd[o]);
            // 5 of the 8 near-shift maps equal T0 here -> join the 72 far shifts
            const float pix = 77.f * __expf(M * invV)
                + __expf((M - Px[o]) * invV)
                + __expf((M - Py[o]) * invV)
                + __expf((M - Pd[o]) * invV);
            const bool ok = xok && (y0 + 4 * ty + o <= 1017);
            tsum += ok ? pix : 0.f;
        }
    } else {
        // ================= GENERAL path: boundary-straddling blocks ============
        float glx[7], ghx[7];
        #pragma unroll
        for (int kx = 0; kx < 7; ++kx) {
            const bool lo = (((x0 - 3 + tx + kx) & 512) == 0);
            glx[kx] = lo ? gk.gh[kx] : 0.f;
            ghx[kx] = lo ? 0.f : gk.gh[kx];
        }
        float Ph[4]  = {0,0,0,0}, Qh[4]  = {0,0,0,0}, Pv[4] = {0,0,0,0}, Qv[4] = {0,0,0,0};
        float Ppp[4] = {0,0,0,0}, Ppm[4] = {0,0,0,0}, Pmp[4] = {0,0,0,0}, Pmm[4] = {0,0,0,0};
        float V4[4]  = {0,0,0,0};
        #pragma unroll
        for (int r = 0; r < 10; ++r) {
            const float4* __restrict__ row = &s1[(4 * ty + r) * SCOLS + tx];
            float hHlo = 0, hHhi = 0, hV = 0, hDlo = 0, hDhi = 0, hU = 0;
            #pragma unroll
            for (int kx = 0; kx < 7; ++kx) {
                const float4 g = row[kx];
                hHlo = fmaf(glx[kx],   g.x, hHlo);
                hHhi = fmaf(ghx[kx],   g.x, hHhi);
                hV   = fmaf(gk.gh[kx], g.y, hV);
                hDlo = fmaf(glx[kx],   g.z, hDlo);
                hDhi = fmaf(ghx[kx],   g.z, hDhi);
                hU   = fmaf(gk.gh[kx], g.w, hU);
            }
            const bool ylo = (((y0 + 4 * ty - 3 + r) & 512) == 0);
            #pragma unroll
            for (int o = 0; o < 4; ++o) {
                if (r - o >= 0 && r - o <= 6) {
                    const float g  = gk.gv[r - o];
                    const float wl = ylo ? g : 0.f;
                    const float wh = ylo ? 0.f : g;
                    Ph [o] = fmaf(g,  hHlo, Ph [o]);
                    Qh [o] = fmaf(g,  hHhi, Qh [o]);
                    Pv [o] = fmaf(wl, hV,   Pv [o]);
                    Qv [o] = fmaf(wh, hV,   Qv [o]);
                    Ppp[o] = fmaf(wl, hDlo, Ppp[o]);
                    Ppm[o] = fmaf(wh, hDlo, Ppm[o]);
                    Pmp[o] = fmaf(wl, hDhi, Pmp[o]);
                    Pmm[o] = fmaf(wh, hDhi, Pmm[o]);
                    V4 [o] = fmaf(g,  hU,   V4 [o]);
                }
            }
        }
        #pragma unroll
        for (int o = 0; o < 4; ++o) {
            const float V = fmaf(V4[o], 0.25f, 1e-5f);
            const float invV = 1.0f / V;
            float M = fminf(0.f, Ph[o]);
            M = fminf(M, Qh[o]);  M = fminf(M, Pv[o]);  M = fminf(M, Qv[o]);
            M = fminf(M, Ppp[o]); M = fminf(M, Pmp[o]); M = fminf(M, Ppm[o]); M = fminf(M, Pmm[o]);
            const float pix = 72.f * __expf(M * invV)
                + __expf((M - Ph [o]) * invV) + __expf((M - Qh [o]) * invV)
                + __expf((M - Pv [o]) * invV) + __expf((M - Qv [o]) * invV)
                + __expf((M - Ppp[o]) * invV) + __expf((M - Pmp[o]) * invV)
                + __expf((M - Ppm[o]) * invV) + __expf((M - Pmm[o]) * invV);
            const bool ok = xok && (y0 + 4 * ty + o <= 1017);
            tsum += ok ? pix : 0.f;
        }
    }

    // ---- per-block partial to workspace (NO fence, NO same-address atomics) ----
    __shared__ float wsum[4];
    const float bt = warp_block_sum(tsum, wsum, tx, ty);
    if (tid == 0)
        partials[(int)blockIdx.y * gridDim.x + (int)blockIdx.x] = bt;
}

__global__ __launch_bounds__(256)
void mind_reduce(const float* __restrict__ partials, float* __restrict__ out)
{
    // 1024 partials, one block
    float s = 0.f;
    #pragma unroll
    for (int k = 0; k < 4; ++k)
        s += partials[(int)threadIdx.x + 256 * k];
    double d = (double)s;
    #pragma unroll
    for (int off = 32; off > 0; off >>= 1)
        d += __shfl_down(d, off, 64);
    __shared__ double sm[4];
    const int lane = (int)threadIdx.x & 63, wid = (int)threadIdx.x >> 6;
    if (lane == 0) sm[wid] = d;
    __syncthreads();
    if (threadIdx.x == 0)
        out[0] = (float)((sm[0] + sm[1] + sm[2] + sm[3]) / 81688800.0);  // 80*1011*1010
}

extern "C" void kernel_launch(void* const* d_in, const int* in_sizes, int n_in,
                              void* d_out, int out_size, void* d_ws, size_t ws_size,
                              hipStream_t stream) {
    const float* img1 = (const float*)d_in[0];
    const float* img2 = (const float*)d_in[1];
    float* out = (float*)d_out;
    float* partials = (float*)d_ws;

    GK gk;
    for (int i = 0; i < 7; ++i) {
        const double dv = i - 3;
        gk.gh[i] = (float)std::exp(-(dv * dv) / 8.0);
        gk.gv[i] = (float)(std::exp(-(dv * dv) / 8.0) / (8.0 * M_PI));
    }

    dim3 block(64, 4);
    dim3 grid(16, 64);   // 16*64 = 1024 blocks
    mind_tile<<<grid, block, 0, stream>>>(img1, img2, partials, gk);
    mind_reduce<<<1, 256, 0, stream>>>(partials, out);
}